// Round 8
// baseline (824.107 us; speedup 1.0000x reference)
//
#include <hip/hip_runtime.h>
#include <hip/hip_bf16.h>
#include <cstddef>

#define TPB 256

typedef float f32x4_t __attribute__((ext_vector_type(4)));
typedef __bf16 bf16x8_t __attribute__((ext_vector_type(8)));
typedef unsigned short u16x8_t __attribute__((ext_vector_type(8)));

// ---------------- workspace layout (float-element offsets) ----------------
static const size_t OFF_X0    = 0;
static const size_t OFF_X1    = 8388608;
static const size_t OFF_X2    = 12582912;
static const size_t OFF_X2H   = 14680064;
static const size_t OFF_X3N   = 16777216;
static const size_t OFF_X3H   = 0;
static const size_t OFF_LAB   = 33554432;
static const size_t OFF_CNT   = 33619968;
static const size_t OFF_STATS = 33620048;
static const size_t OFF_GBINS = 33622096;
static const size_t OFF_NST0  = 33663056;
static const size_t OFF_NST1  = 33663312;
static const size_t OFF_NST2  = 33663824;
static const size_t OFF_WPH   = 42008704;
static const size_t OFF_WPL   = 42598528;
static const size_t OFF_WTPH  = 8388608;
static const size_t OFF_WTPL  = 8536064;

__device__ __forceinline__ unsigned short f2bf(float f) {
    unsigned int u = __float_as_uint(f);
    unsigned int r = u + 0x7FFFu + ((u >> 16) & 1u);   // RNE (finite inputs)
    return (unsigned short)(r >> 16);
}
__device__ __forceinline__ float bf2f(unsigned short h) {
    return __uint_as_float(((unsigned int)h) << 16);
}
__device__ __forceinline__ void gload16(const unsigned short* g, unsigned short* l) {
    __builtin_amdgcn_global_load_lds((const __attribute__((address_space(1))) unsigned int*)g,
                                     (__attribute__((address_space(3))) unsigned int*)l, 16, 0, 0);
}

// ---------------- conv0: 3->32, 256x256, reflect pad 1 ----------------
__global__ __launch_bounds__(256) void conv0b_kernel(const float* __restrict__ x,
                                                     const float* __restrict__ w,
                                                     const float* __restrict__ bias,
                                                     float* __restrict__ y) {
    __shared__ float lw[3 * 9 * 32];                 // [c][t][o]
    int pix = blockIdx.x * TPB + threadIdx.x;
    int i = pix >> 8, j = pix & 255;
    int b = blockIdx.y;
    for (int k = threadIdx.x; k < 864; k += TPB) {
        int o = k & 31; int ct = k >> 5; int t = ct % 9; int c = ct / 9;
        lw[k] = w[((size_t)o * 3 + c) * 9 + t];
    }
    __syncthreads();
    float acc[32];
#pragma unroll
    for (int o = 0; o < 32; ++o) acc[o] = bias[o];
    const float* xb = x + (size_t)b * 3 * 65536;
    for (int c = 0; c < 3; ++c) {
        const float* xc = xb + c * 65536;
        float xv[9];
#pragma unroll
        for (int u = 0; u < 3; ++u) {
            int ii = i + u - 1; ii = ii < 0 ? 1 : (ii > 255 ? 254 : ii);
#pragma unroll
            for (int v = 0; v < 3; ++v) {
                int jj = j + v - 1; jj = jj < 0 ? 1 : (jj > 255 ? 254 : jj);
                xv[u * 3 + v] = xc[(ii << 8) + jj];
            }
        }
        const float* lwc = &lw[c * 288];
#pragma unroll
        for (int t = 0; t < 9; ++t)
#pragma unroll
            for (int o4 = 0; o4 < 8; ++o4) {
                float4 w4 = *(const float4*)&lwc[t * 32 + o4 * 4];
                acc[o4 * 4 + 0] += xv[t] * w4.x;
                acc[o4 * 4 + 1] += xv[t] * w4.y;
                acc[o4 * 4 + 2] += xv[t] * w4.z;
                acc[o4 * 4 + 3] += xv[t] * w4.w;
            }
    }
    float* yb = y + (size_t)b * 32 * 65536;
#pragma unroll
    for (int o = 0; o < 32; ++o) yb[(size_t)o * 65536 + pix] = acc[o];
}

// ---------------- instance norm, split stats/apply (NCHW, in place) ----------------
__global__ void in_stats_nchw_kernel(const float* __restrict__ x, float* __restrict__ st,
                                     int HWs, int HW) {
    const float* p = x + (size_t)blockIdx.x * HW + (size_t)blockIdx.y * HWs;
    float s = 0.0f, ss = 0.0f;
    for (int k = threadIdx.x; k < HWs; k += TPB) { float v = p[k]; s += v; ss += v * v; }
#pragma unroll
    for (int o = 32; o > 0; o >>= 1) { s += __shfl_down(s, o); ss += __shfl_down(ss, o); }
    __shared__ float sh[2][4];
    int wv = threadIdx.x >> 6;
    if ((threadIdx.x & 63) == 0) { sh[0][wv] = s; sh[1][wv] = ss; }
    __syncthreads();
    if (threadIdx.x == 0) {
        atomicAdd(&st[blockIdx.x * 2],     sh[0][0] + sh[0][1] + sh[0][2] + sh[0][3]);
        atomicAdd(&st[blockIdx.x * 2 + 1], sh[1][0] + sh[1][1] + sh[1][2] + sh[1][3]);
    }
}
__global__ void in_apply_nchw_kernel(float* __restrict__ x, const float* __restrict__ st,
                                     int logHW, float rHW, int n4) {
    int id = blockIdx.x * TPB + threadIdx.x;
    if (id >= n4) return;
    int bc = (int)(((size_t)id << 2) >> logHW);
    float s = st[bc * 2], ss = st[bc * 2 + 1];
    float m = s * rHW;
    float inv = rsqrtf(ss * rHW - m * m + 1e-5f);
    float4* px4 = (float4*)x;
    float4 v = px4[id];
    v.x = (v.x - m) * inv; v.x = v.x >= 0.0f ? v.x : 0.2f * v.x;
    v.y = (v.y - m) * inv; v.y = v.y >= 0.0f ? v.y : 0.2f * v.y;
    v.z = (v.z - m) * inv; v.z = v.z >= 0.0f ? v.z : 0.2f * v.z;
    v.w = (v.w - m) * inv; v.w = v.w >= 0.0f ? v.w : 0.2f * v.w;
    px4[id] = v;
}

// ---------------- strided conv (stride 2, zero pad 1), broadcast weights ----------------
template<int IC, int IH, int IW, int OH, int OW, int OCT>
__global__ __launch_bounds__(256) void conv_s2b_kernel(const float* __restrict__ x,
                                                       const float* __restrict__ w,
                                                       const float* __restrict__ bias,
                                                       float* __restrict__ y, int OC) {
    __shared__ float lw[IC * 9 * OCT];               // [c][t][o]
    int p2 = (blockIdx.x * TPB + threadIdx.x) * 2;
    int i = p2 / OW, j = p2 % OW;
    int ocg = blockIdx.y, b = blockIdx.z;
    for (int k = threadIdx.x; k < IC * 9 * OCT; k += TPB) {
        int o = k & (OCT - 1); int ct = k / OCT; int t = ct % 9; int c = ct / 9;
        lw[k] = w[((size_t)(ocg * OCT + o) * IC + c) * 9 + t];
    }
    __syncthreads();
    float acc0[OCT], acc1[OCT];
#pragma unroll
    for (int o = 0; o < OCT; ++o) { float bv = bias[ocg * OCT + o]; acc0[o] = bv; acc1[o] = bv; }
    const float* xb = x + (size_t)b * IC * IH * IW;
    for (int c = 0; c < IC; ++c) {
        const float* xc = xb + (size_t)c * IH * IW;
        float xr[3][5];
#pragma unroll
        for (int u = 0; u < 3; ++u) {
            int ii = 2 * i + u - 1;
            bool vr = (ii >= 0);
#pragma unroll
            for (int vv = 0; vv < 5; ++vv) {
                int jj = 2 * j + vv - 1;
                xr[u][vv] = (vr && jj >= 0) ? xc[ii * IW + jj] : 0.0f;
            }
        }
        const float* lwc = &lw[c * 9 * OCT];
#pragma unroll
        for (int u = 0; u < 3; ++u)
#pragma unroll
            for (int v = 0; v < 3; ++v) {
                float a = xr[u][v], bx = xr[u][v + 2];
#pragma unroll
                for (int o4 = 0; o4 < OCT / 4; ++o4) {
                    float4 w4 = *(const float4*)&lwc[(u * 3 + v) * OCT + o4 * 4];
                    acc0[o4 * 4 + 0] += a * w4.x;  acc1[o4 * 4 + 0] += bx * w4.x;
                    acc0[o4 * 4 + 1] += a * w4.y;  acc1[o4 * 4 + 1] += bx * w4.y;
                    acc0[o4 * 4 + 2] += a * w4.z;  acc1[o4 * 4 + 2] += bx * w4.z;
                    acc0[o4 * 4 + 3] += a * w4.w;  acc1[o4 * 4 + 3] += bx * w4.w;
                }
            }
    }
    float* yb = y + ((size_t)(b * OC) + ocg * OCT) * (size_t)(OH * OW) + p2;
#pragma unroll
    for (int o = 0; o < OCT; ++o) {
        float2 v2 = make_float2(acc0[o], acc1[o]);
        *(float2*)&yb[(size_t)o * OH * OW] = v2;
    }
}

// ---------------- transpose+split x2: [4,128,64,64] f32 -> [2][4,64,64,128] bf16 ----------------
__global__ void transpose_x2_kernel(const float* __restrict__ x2, unsigned short* __restrict__ x2h) {
    __shared__ __align__(16) unsigned short tileH[64][136];
    __shared__ __align__(16) unsigned short tileL[64][136];
    int h = blockIdx.x, b = blockIdx.y;
    int t = threadIdx.x;
    int px = t & 63, c4 = t >> 6;
    const float* src = x2 + ((size_t)b * 128) * 4096 + h * 64 + px;
#pragma unroll
    for (int k = 0; k < 32; ++k) {
        int c = c4 * 32 + k;
        float v = src[(size_t)c * 4096];
        unsigned short hb = f2bf(v);
        tileH[px][c] = hb;
        tileL[px][c] = f2bf(v - bf2f(hb));
    }
    __syncthreads();
    unsigned short* dh = x2h + ((size_t)(b * 64 + h) * 64) * 128;
#pragma unroll
    for (int k = 0; k < 4; ++k) {
        int chunk = k * 256 + t;
        int p2 = chunk >> 4, c8 = (chunk & 15) << 3;
        *(u16x8_t*)&dh[(size_t)p2 * 128 + c8] = *(const u16x8_t*)&tileH[p2][c8];
        *(u16x8_t*)&dh[2097152 + (size_t)p2 * 128 + c8] = *(const u16x8_t*)&tileL[p2][c8];
    }
}

// ---------------- weight packs ----------------
__global__ void packw_kernel(const float* __restrict__ w3, unsigned short* __restrict__ wph,
                             unsigned short* __restrict__ wpl) {
    int id = blockIdx.x * TPB + threadIdx.x;
    if (id >= 9 * 512 * 256) return;
    int c = id & 255; int to = id >> 8; int o = to & 511; int tt = to >> 9;
    float v = w3[((size_t)o * 256 + c) * 9 + tt];
    unsigned short hb = f2bf(v);
    wph[id] = hb;
    wpl[id] = f2bf(v - bf2f(hb));
}
__global__ void packwt_kernel(const float* __restrict__ wt, unsigned short* __restrict__ wph,
                              unsigned short* __restrict__ wpl) {
    int id = blockIdx.x * TPB + threadIdx.x;
    if (id >= 9 * 256 * 128) return;
    int c = id & 127; int to = id >> 7; int o = to & 255; int tt = to >> 8;
    float v = wt[((size_t)o * 128 + c) * 9 + tt];
    unsigned short hb = f2bf(v);
    wph[id] = hb;
    wpl[id] = f2bf(v - bf2f(hb));
}

// ---------------- convT 128->256 MFMA, all 4 parity classes, fused stats ----------------
// amdgpu_waves_per_eu(2): 8-wave block + big LDS can only run 2 waves/EU anyway;
// without it the backend budgets registers for 4 waves/EU (128 cap) and spills.
__global__ __launch_bounds__(512) __attribute__((amdgpu_waves_per_eu(2)))
void convt_mfma_all_kernel(
    const unsigned short* __restrict__ xh, const unsigned short* __restrict__ wh,
    const unsigned short* __restrict__ wl, const float* __restrict__ bias,
    float* __restrict__ y, float* __restrict__ stats) {
    __shared__ __align__(16) unsigned short ldsW[4][2][64][32];
    __shared__ __align__(16) unsigned short ldsXh[9][66][32];
    __shared__ __align__(16) unsigned short ldsXl[9][66][32];
    __shared__ float sums[64][2];
    int ocg = blockIdx.x, a0 = blockIdx.y * 8;
    int b = blockIdx.z >> 2, cls = blockIdx.z & 3;
    int pi = cls >> 1, pj = cls & 1;
    int nt = (pi + 1) * (pj + 1);
    int tid = threadIdx.x;
    int l = tid & 63, w = tid >> 6;
    int px = l & 15, g = l >> 4;

    f32x4_t acc[4][4];                       // [j (bb frag)][m (oc frag)]
#pragma unroll
    for (int m = 0; m < 4; ++m) {
        float bv = bias[ocg * 64 + 16 * m + px];
#pragma unroll
        for (int j = 0; j < 4; ++j)
#pragma unroll
            for (int r = 0; r < 4; ++r) acc[j][m][r] = bv;
    }
    unsigned short* ldsXhf = &ldsXh[0][0][0];
    unsigned short* ldsXlf = &ldsXl[0][0][0];

    for (int cc = 0; cc < 128; cc += 32) {
        __syncthreads();
        for (int k = 0; k < nt; ++k) {
            int iu = pj ? (k >> 1) : k;
            int iv = pj ? (k & 1) : 0;
            int u = pi ? iu * 2 : 1;
            int v = pj ? iv * 2 : 1;
            int tap = 3 * u + v;
            int gq = tid & 3;
            int o = (tid >> 2) & 63;
            int h = (tid >> 8) & 1;
            const unsigned short* srcp = (h ? wl : wh) +
                ((size_t)tap * 256 + ocg * 64 + o) * 128 + cc + (gq << 3);
            *(u16x8_t*)&ldsW[k][h][o][(gq ^ (o & 3)) << 3] = *(const u16x8_t*)srcp;
        }
        for (int k = 0; k < 5; ++k) {
            int c16 = k * 512 + tid;
            if (c16 < 2376) {
                int gq = c16 & 3;
                int rc = c16 >> 2;
                int row = (rc * 993) >> 16;
                int col = rc - row * 66;
                int gr = a0 + row;
                u16x8_t vh = {}, vl = {};
                if (gr < 64 && col < 64) {
                    size_t sidx = (((size_t)(b * 64 + gr) * 64) + col) * 128 + cc + (gq << 3);
                    vh = *(const u16x8_t*)(xh + sidx);
                    vl = *(const u16x8_t*)(xh + 2097152 + sidx);
                }
                int off = ((rc << 2) | (gq ^ (col & 3))) << 3;
                *(u16x8_t*)(ldsXhf + off) = vh;
                *(u16x8_t*)(ldsXlf + off) = vl;
            }
        }
        __syncthreads();
        for (int k = 0; k < nt; ++k) {
            int dr = pj ? (k >> 1) : k;
            int dc = pj ? (k & 1) : 0;
            bf16x8_t Xh4[4], Xl4[4], Wh4[4], Wl4[4];
#pragma unroll
            for (int j = 0; j < 4; ++j) {
                int col = dc + 16 * j + px;
                int sl = (g ^ (col & 3)) << 3;
                Xh4[j] = *(const bf16x8_t*)&ldsXh[w + dr][col][sl];
                Xl4[j] = *(const bf16x8_t*)&ldsXl[w + dr][col][sl];
            }
            int sA = (g ^ (px & 3)) << 3;
#pragma unroll
            for (int m = 0; m < 4; ++m) {
                Wh4[m] = *(const bf16x8_t*)&ldsW[k][0][16 * m + px][sA];
                Wl4[m] = *(const bf16x8_t*)&ldsW[k][1][16 * m + px][sA];
            }
#pragma unroll
            for (int j = 0; j < 4; ++j)
#pragma unroll
                for (int m = 0; m < 4; ++m) {
                    acc[j][m] = __builtin_amdgcn_mfma_f32_16x16x32_bf16(Xh4[j], Wh4[m], acc[j][m], 0, 0, 0);
                    acc[j][m] = __builtin_amdgcn_mfma_f32_16x16x32_bf16(Xh4[j], Wl4[m], acc[j][m], 0, 0, 0);
                    acc[j][m] = __builtin_amdgcn_mfma_f32_16x16x32_bf16(Xl4[j], Wh4[m], acc[j][m], 0, 0, 0);
                }
        }
    }
    if (tid < 128) (&sums[0][0])[tid] = 0.0f;
    __syncthreads();
    int orow = 2 * (a0 + w) + pi;
    float* yb = y + (((size_t)(b * 128 + orow) * 128)) * 256 + ocg * 64;
#pragma unroll
    for (int m = 0; m < 4; ++m) {
        float sm = 0.0f, ssm = 0.0f;
#pragma unroll
        for (int j = 0; j < 4; ++j)
#pragma unroll
            for (int r = 0; r < 4; ++r) {
                float val = acc[j][m][r];
                sm += val; ssm += val * val;
                int bb = 16 * j + 4 * g + r;
                yb[(size_t)(2 * bb + pj) * 256 + 16 * m + px] = val;
            }
        sm  += __shfl_xor(sm, 16);  sm  += __shfl_xor(sm, 32);
        ssm += __shfl_xor(ssm, 16); ssm += __shfl_xor(ssm, 32);
        if (g == 0) {
            atomicAdd(&sums[16 * m + px][0], sm);
            atomicAdd(&sums[16 * m + px][1], ssm);
        }
    }
    __syncthreads();
    if (tid < 64) {
        atomicAdd(&stats[((size_t)(b * 256) + ocg * 64 + tid) * 2 + 0], sums[tid][0]);
        atomicAdd(&stats[((size_t)(b * 256) + ocg * 64 + tid) * 2 + 1], sums[tid][1]);
    }
}

// ---------------- NHWC instance-norm apply (x3n -> x3h bf16), vectorized ----------------
__global__ void in_apply_nhwc_kernel(const float* __restrict__ x, const float* __restrict__ stats,
                                     unsigned short* __restrict__ xhout) {
    __shared__ float sm[256], sinv[256];
    int row = blockIdx.x, b = blockIdx.y;
    int tid = threadIdx.x;
    {
        float s = stats[(b * 256 + tid) * 2], ss = stats[(b * 256 + tid) * 2 + 1];
        float mm = s * (1.0f / 16384.0f);
        sm[tid] = mm;
        sinv[tid] = rsqrtf(ss * (1.0f / 16384.0f) - mm * mm + 1e-5f);
    }
    __syncthreads();
    const float* xr = x + ((size_t)(b * 128 + row) * 128) * 256;
    unsigned short* qr = xhout + ((size_t)(b * 128 + row) * 128) * 256;
    for (int idx = tid; idx < 128 * 32; idx += TPB) {
        int col = idx >> 5, c8 = (idx & 31) << 3;
        const float* p = xr + col * 256 + c8;
        float4 v0 = *(const float4*)p;
        float4 v1 = *(const float4*)(p + 4);
        float vs[8] = {v0.x, v0.y, v0.z, v0.w, v1.x, v1.y, v1.z, v1.w};
        u16x8_t o;
#pragma unroll
        for (int q = 0; q < 8; ++q) {
            int c = c8 + q;
            float f = (vs[q] - sm[c]) * sinv[c];
            f = f >= 0.0f ? f : 0.2f * f;
            o[q] = f2bf(f);
        }
        *(u16x8_t*)&qr[col * 256 + c8] = o;
    }
}

// ---------------- conv3 fused: 256->512 MFMA + tanh + segment-sum binning ----------------
// Wave: 64 oc x 2 rows x 64 cols (acc 4x8 = 128 regs). Block: 8 waves.
// amdgpu_waves_per_eu(2): without it the backend budgets for 4 waves/EU ->
// 128-reg cap -> ~330MB scratch spill (r4-r6). 8-wave block + 155KB LDS can
// only run 2 waves/EU anyway, so budget = 512/2 = 256 regs/wave.
__global__ __launch_bounds__(512) __attribute__((amdgpu_waves_per_eu(2)))
void conv3_fused_kernel(
    const unsigned short* __restrict__ xh, const unsigned short* __restrict__ wh,
    const unsigned short* __restrict__ wl, const float* __restrict__ bias,
    const int* __restrict__ lab, float* __restrict__ gbins) {
    __shared__ __align__(16) unsigned short ldsW[9][2][64][32];   // 73,728 B
    __shared__ __align__(16) unsigned short ldsX[18][66][32];     // 76,032 B
    __shared__ float bins[20][64];                                // 5,120 B  (tot 154,880)
    int lin = blockIdx.x;
    int gid = lin & 7;                 // XCD group (round-robin assumption)
    int pos = lin >> 3;                // 0..63
    int ocg = (gid >> 1) * 2 + (pos & 1);
    int inst = (gid & 1) * 32 + (pos >> 1);
    int b = inst >> 4;
    int ty = inst & 15;
    int r0 = (ty >> 1) * 16, c0 = (ty & 1) * 64;
    int tid = threadIdx.x;
    int l = tid & 63, w = tid >> 6;
    int px = l & 15, g = l >> 4;
    int wslot = w << 6;

    for (int k = tid; k < 1280; k += 512) (&bins[0][0])[k] = 0.0f;

    f32x4_t acc[4][8];
#pragma unroll
    for (int m = 0; m < 4; ++m)
#pragma unroll
        for (int r = 0; r < 4; ++r) {
            float bv = bias[(ocg << 6) + 16 * m + 4 * g + r];
#pragma unroll
            for (int n = 0; n < 8; ++n) acc[m][n][r] = bv;
        }

    const unsigned short* xbase = xh + (size_t)b * (128 * 128 * 256);
    unsigned short* ldsWf = &ldsW[0][0][0][0];
    unsigned short* ldsXf = &ldsX[0][0][0];

    for (int cc = 0; cc < 256; cc += 32) {
        __syncthreads();                       // prev chunk's readers done
        // ---- stage W via global_load_lds: 4608 chunks (9 iters) ----
#pragma unroll
        for (int k = 0; k < 9; ++k) {
            int base = (k << 9) + wslot;       // wave-uniform
            int c16 = base + l;
            int gq = c16 & 3;
            int hto = c16 >> 2;
            int o = hto & 63;
            int th = hto >> 6;
            int h = th & 1, ttap = th >> 1;
            const unsigned short* srcp = (h ? wl : wh) +
                (((size_t)ttap * 512 + (ocg << 6) + o) << 8) + cc + (gq << 3);
            gload16(srcp, ldsWf + ((size_t)base << 3));
        }
        // ---- stage X: 4752 chunks, 10 iters (last partial) ----
#pragma unroll
        for (int k = 0; k < 10; ++k) {
            int base = (k << 9) + wslot;
            int c16 = base + l;
            if (c16 < 4752) {
                int gq = c16 & 3;
                int rc = c16 >> 2;
                int row = (rc * 993) >> 16;    // rc / 66
                int col = rc - row * 66;
                int gi = r0 + row - 1; gi = gi < 0 ? 1 : (gi > 127 ? 126 : gi);
                int gj = c0 + col - 1; gj = gj < 0 ? 1 : (gj > 127 ? 126 : gj);
                const unsigned short* srcp = xbase + ((((size_t)gi << 7) + gj) << 8) + cc + (gq << 3);
                gload16(srcp, ldsXf + ((size_t)base << 3));
            }
        }
        __syncthreads();                       // drains vmcnt (compiler) + barrier
        // ---- compute ----
#pragma unroll
        for (int u = 0; u < 3; ++u) {
#pragma unroll
            for (int v = 0; v < 3; ++v) {
                int t3 = 3 * u + v;
                bf16x8_t Ah[4], Al[4];
#pragma unroll
                for (int m = 0; m < 4; ++m) {
                    Ah[m] = *(const bf16x8_t*)&ldsW[t3][0][16 * m + px][g << 3];
                    Al[m] = *(const bf16x8_t*)&ldsW[t3][1][16 * m + px][g << 3];
                }
#pragma unroll
                for (int d = 0; d < 2; ++d) {
                    bf16x8_t Bf[4];
#pragma unroll
                    for (int jj = 0; jj < 4; ++jj)
                        Bf[jj] = *(const bf16x8_t*)&ldsX[2 * w + d + u][v + 16 * jj + px][g << 3];
#pragma unroll
                    for (int m = 0; m < 4; ++m)
#pragma unroll
                        for (int jj = 0; jj < 4; ++jj)
                            acc[m][d * 4 + jj] = __builtin_amdgcn_mfma_f32_16x16x32_bf16(
                                Ah[m], Bf[jj], acc[m][d * 4 + jj], 0, 0, 0);
#pragma unroll
                    for (int m = 0; m < 4; ++m)
#pragma unroll
                        for (int jj = 0; jj < 4; ++jj)
                            acc[m][d * 4 + jj] = __builtin_amdgcn_mfma_f32_16x16x32_bf16(
                                Al[m], Bf[jj], acc[m][d * 4 + jj], 0, 0, 0);
                }
            }
        }
    }
    // ---- epilogue: tanh + bin by label ----
    int labs[2][4];
#pragma unroll
    for (int d = 0; d < 2; ++d) {
        const int* lrow = lab + (b << 14) + ((r0 + 2 * w + d) << 7) + c0;
#pragma unroll
        for (int jj = 0; jj < 4; ++jj) labs[d][jj] = lrow[16 * jj + px];
    }
#pragma unroll
    for (int m = 0; m < 4; ++m)
#pragma unroll
        for (int r = 0; r < 4; ++r) {
            int oc = 16 * m + 4 * g + r;
#pragma unroll
            for (int d = 0; d < 2; ++d)
#pragma unroll
                for (int jj = 0; jj < 4; ++jj) {
                    int lb = labs[d][jj];
                    if (lb >= 0) atomicAdd(&bins[lb][oc], tanhf(acc[m][d * 4 + jj][r]));
                }
        }
    __syncthreads();
    for (int k = tid; k < 1280; k += 512) {
        int s = k >> 6, oc = k & 63;
        float v = bins[s][oc];
        if (v != 0.0f)
            atomicAdd(&gbins[(((size_t)b * 20 + s) << 9) + (ocg << 6) + oc], v);
    }
}

// ---------------- labels + counts ----------------
__global__ void label_kernel(const float* __restrict__ seg, const float* __restrict__ fg,
                             int* __restrict__ lab, float* __restrict__ counts) {
    int b = blockIdx.y;
    int pix = blockIdx.x * TPB + threadIdx.x;
    int i = pix >> 7, j = pix & 127;
    int src = ((i * 2) << 8) + (j * 2);
    const float* fgb = fg + (size_t)b * 65536;
    int l = -1;
    if (fgb[src] == 0.0f) {
        const float* sb = seg + (size_t)b * 20 * 65536;
        for (int s = 0; s < 20; ++s)
            if (sb[(size_t)s * 65536 + src] != 0.0f) { l = s; break; }
    }
    lab[b * 16384 + pix] = l;
    __shared__ int bins[20];
    if (threadIdx.x < 20) bins[threadIdx.x] = 0;
    __syncthreads();
    if (l >= 0) atomicAdd(&bins[l], 1);
    __syncthreads();
    if (threadIdx.x < 20 && bins[threadIdx.x] > 0)
        atomicAdd(&counts[b * 20 + threadIdx.x], (float)bins[threadIdx.x]);
}

// ---------------- final divide: out = gbins / counts ----------------
__global__ void segdiv_kernel(const float* __restrict__ gbins, const float* __restrict__ cnt,
                              float* __restrict__ out) {
    int id = blockIdx.x * TPB + threadIdx.x;
    if (id >= 4 * 20 * 512) return;
    int bs = id >> 9;
    float c = cnt[bs];
    out[id] = c > 0.0f ? gbins[id] / c : 0.0f;
}

// ---------------- launch ----------------
extern "C" void kernel_launch(void* const* d_in, const int* in_sizes, int n_in,
                              void* d_out, int out_size, void* d_ws, size_t ws_size,
                              hipStream_t stream) {
    const float* input = (const float*)d_in[0];
    const float* segmap = (const float*)d_in[1];
    const float* fg = (const float*)d_in[2];
    const float* w0 = (const float*)d_in[3];  const float* b0 = (const float*)d_in[4];
    const float* w1 = (const float*)d_in[5];  const float* b1 = (const float*)d_in[6];
    const float* w2 = (const float*)d_in[7];  const float* b2 = (const float*)d_in[8];
    const float* wt = (const float*)d_in[9];  const float* bt = (const float*)d_in[10];
    const float* w3 = (const float*)d_in[11]; const float* b3 = (const float*)d_in[12];

    float* ws = (float*)d_ws;
    float* x0 = ws + OFF_X0;
    float* x1 = ws + OFF_X1;
    float* x2 = ws + OFF_X2;
    unsigned short* x2h = (unsigned short*)(ws + OFF_X2H);
    float* x3n = ws + OFF_X3N;
    unsigned short* x3h = (unsigned short*)(ws + OFF_X3H);
    int*   lab = (int*)(ws + OFF_LAB);
    float* cnt = ws + OFF_CNT;
    float* stats = ws + OFF_STATS;
    float* gbins = ws + OFF_GBINS;
    float* nst0 = ws + OFF_NST0;
    float* nst1 = ws + OFF_NST1;
    float* nst2 = ws + OFF_NST2;
    unsigned short* wph = (unsigned short*)(ws + OFF_WPH);
    unsigned short* wpl = (unsigned short*)(ws + OFF_WPL);
    unsigned short* wtph = (unsigned short*)(ws + OFF_WTPH);
    unsigned short* wtpl = (unsigned short*)(ws + OFF_WTPL);
    float* out = (float*)d_out;

    // zero cnt+stats+gbins+nst in one shot (contiguous region)
    hipMemsetAsync(ws + OFF_CNT, 0, (OFF_NST2 + 1024 - OFF_CNT) * sizeof(float), stream);
    // conv3 weight pack (independent)
    packw_kernel<<<dim3(4608), TPB, 0, stream>>>(w3, wph, wpl);
    // stage 0: conv0 + IN + lrelu -> x0
    conv0b_kernel<<<dim3(256, 4), TPB, 0, stream>>>(input, w0, b0, x0);
    in_stats_nchw_kernel<<<dim3(128, 8), TPB, 0, stream>>>(x0, nst0, 8192, 65536);
    in_apply_nchw_kernel<<<dim3(8192), TPB, 0, stream>>>(x0, nst0, 16, 1.0f / 65536.0f, 2097152);
    // stage 1: s2 conv 32->64 + IN + lrelu -> x1
    conv_s2b_kernel<32, 256, 256, 128, 128, 16><<<dim3(32, 4, 4), TPB, 0, stream>>>(x0, w1, b1, x1, 64);
    in_stats_nchw_kernel<<<dim3(256, 2), TPB, 0, stream>>>(x1, nst1, 8192, 16384);
    in_apply_nchw_kernel<<<dim3(4096), TPB, 0, stream>>>(x1, nst1, 14, 1.0f / 16384.0f, 1048576);
    // stage 2: s2 conv 64->128 + IN + lrelu -> x2
    conv_s2b_kernel<64, 128, 128, 64, 64, 16><<<dim3(8, 8, 4), TPB, 0, stream>>>(x1, w2, b2, x2, 128);
    packwt_kernel<<<dim3(1152), TPB, 0, stream>>>(wt, wtph, wtpl);
    in_stats_nchw_kernel<<<dim3(512, 1), TPB, 0, stream>>>(x2, nst2, 4096, 4096);
    in_apply_nchw_kernel<<<dim3(2048), TPB, 0, stream>>>(x2, nst2, 12, 1.0f / 4096.0f, 524288);
    // stage 3: transpose x2 -> NHWC bf16 hi/lo; convT (all classes, fused stats) -> x3n
    transpose_x2_kernel<<<dim3(64, 4), TPB, 0, stream>>>(x2, x2h);
    convt_mfma_all_kernel<<<dim3(4, 8, 16), 512, 0, stream>>>(x2h, wtph, wtpl, bt, x3n, stats);
    // stage 3.5: NHWC IN + lrelu + bf16 convert -> x3h
    in_apply_nhwc_kernel<<<dim3(128, 4), TPB, 0, stream>>>(x3n, stats, x3h);
    // stage 5a: labels + counts (before conv3)
    label_kernel<<<dim3(64, 4), TPB, 0, stream>>>(segmap, fg, lab, cnt);
    // stage 4+5b: conv3 (bf16 MFMA, split-A) + tanh + fused segment sums
    conv3_fused_kernel<<<dim3(512), 512, 0, stream>>>(x3h, wph, wpl, b3, lab, gbins);
    // stage 5c: divide
    segdiv_kernel<<<dim3(160), TPB, 0, stream>>>(gbins, cnt, out);
}